// Round 5
// baseline (276.786 us; speedup 1.0000x reference)
//
#include <hip/hip_runtime.h>
#include <math.h>

// Problem constants (fixed by setup_inputs)
#define B_    2
#define L_    4096
#define H_    8
#define D_    64
#define S_    45      // sample_k
#define NT_   45      // n_top
#define BH_   16      // B*H
#define CHV   64      // cumsum chunk length
#define NCHV  64      // L_/CHV
#define KC    128     // attention key-chunk length
#define NKC   32      // L_/KC
#define SCALE 0.125f  // 1/sqrt(64)
#define NEG_BIG (-1e30f)

// Workspace layout (float element offsets; ints share the same 4B slots).
// VSUM is only live between kA and kB-part2; CTXP is written in kC, so
// VSUM overlays the start of the CTXP region. Total ~6.35 MB (proven size).
#define OFF_M     0         // 65536 floats: M[bh][q]
#define OFF_MTOP  65536     // 720 ints:    M_top[bh][u]
#define OFF_MPART 66304     // 23040 floats: m partial [bh][u][kc]
#define OFF_SPART 89344     // 23040 floats: sumexp partial [bh][u][kc]
#define OFF_CTXP  112384    // 1474560 floats: ctx partial [bh][kc][u][d]
#define OFF_VSUM  112384    // 65536 floats: vsum[bh][ch][d] (overlays CTXP)

// DPP row-rotate combine: rotations by 1,2,4,8 within a 16-lane row.
// VALU-pipe (no ds_swizzle), full-rate. All lanes/masks enabled -> old unused.
template <int CTRL>
__device__ __forceinline__ float dpp_ror_f(float x) {
    int y = __builtin_amdgcn_update_dpp(0, __float_as_int(x), CTRL, 0xF, 0xF, false);
    return __int_as_float(y);
}

// ---------------------------------------------------------------------------
// Kernel A: part 1 (blocks < 16384): block = (b, q, hh) with 128 threads.
//   XCD-slab swizzle: blockIdx%8 = XCD (round-robin dispatch); slab
//   (b,hh) = 4096 rows x 1KB = 4MB = one XCD's L2.
//   Per sample one coalesced 1KB load covers 4 heads (lane = 16B chunk);
//   dot4 + 4-step DPP row-rotate reduce in 16-lane head groups.
//           part 2 (blocks >= 16384): per-chunk V sums, 16 loads in flight.
// ---------------------------------------------------------------------------
__global__ __launch_bounds__(128) void kA(const float* __restrict__ Q,
                                          const float* __restrict__ Kt,
                                          const float* __restrict__ V,
                                          const int* __restrict__ samp,
                                          float* __restrict__ ws)
{
    int tid  = threadIdx.x;
    int w    = tid >> 6;          // 0..1
    int lane = tid & 63;

    if (blockIdx.x < 16384) {
        // i%8 = XCD; slab = xcd>>1 in [0,4): b = slab>>1, hh = slab&1
        int i   = blockIdx.x;
        int xcd = i & 7;
        int b   = xcd >> 2;
        int hh  = (xcd >> 1) & 1;
        int q   = ((i >> 3) << 1) | (xcd & 1);   // 2048 j-slots x 2 = 4096 q

        __shared__ int   sidx[S_];
        __shared__ float redm[4][2], reds[4][2];

        if (tid < S_) sidx[tid] = samp[q * S_ + tid];
        __syncthreads();

        int sh = w;                   // sample-half
        int h4 = lane >> 4;           // head within half
        int h  = hh * 4 + h4;

        const float4 q4 = *(const float4*)(Q +
            ((((long)b * L_ + q) * H_ + hh * 4) << 6) + lane * 4);

        const float* kb_base = Kt + (((long)b * L_ * H_ + hh * 4) << 6) + lane * 4;

        // sh=0 covers s=0..22, sh=1 covers s=22..44 (s=22 dup: max-safe,
        // masked out of the sum). 24 trips (last clamped), 12-deep batches.
        float mx = NEG_BIG, sm = 0.f;
#pragma unroll
        for (int jb = 0; jb < 24; jb += 12) {
            float4 kb[12];
#pragma unroll
            for (int j = 0; j < 12; ++j) {
                int jj = jb + j;
                int jc = jj < 23 ? jj : 22;            // clamp 24th trip
                int s  = sh * 22 + jc;
                kb[j] = *(const float4*)(kb_base + (((long)sidx[s] * H_) << 6));
            }
#pragma unroll
            for (int j = 0; j < 12; ++j) {
                int jj = jb + j;
                float p = q4.x * kb[j].x + q4.y * kb[j].y +
                          q4.z * kb[j].z + q4.w * kb[j].w;
                p += dpp_ror_f<0x121>(p);   // ror 1
                p += dpp_ror_f<0x122>(p);   // ror 2
                p += dpp_ror_f<0x124>(p);   // ror 4
                p += dpp_ror_f<0x128>(p);   // ror 8 -> row sum (16 lanes)
                mx = fmaxf(mx, p);          // duplicates harmless for max
                bool valid = (jj < 23) && !(sh == 1 && jj == 0);
                sm += valid ? p : 0.f;
            }
        }
        if ((lane & 15) == 0) { redm[h4][sh] = mx; reds[h4][sh] = sm; }
        __syncthreads();
        if (tid < 4) {
            float m = fmaxf(redm[tid][0], redm[tid][1]);
            float s = reds[tid][0] + reds[tid][1];
            ws[OFF_M + ((long)(b * 8 + hh * 4 + tid)) * L_ + q] = m - s * (1.0f / (float)L_);
        }
    } else {
        // wave per (bh, ch): vsum[bh][ch][d] = sum_{i<CHV} V[b, ch*CHV+i, h, d]
        int unit = (blockIdx.x - 16384) * 2 + w;   // 0..1023
        int bh = unit >> 6, ch = unit & 63;
        int b = bh >> 3, h = bh & 7;
        int d = lane;
        const float* vp = V + ((((long)b * L_ + (long)ch * CHV) * H_ + h) << 6) + d;
        float ssum = 0.f;
#pragma unroll
        for (int ib = 0; ib < CHV; ib += 16) {
            float vb[16];
#pragma unroll
            for (int j = 0; j < 16; ++j) vb[j] = vp[(long)(ib + j) * (H_ * D_)];
#pragma unroll
            for (int j = 0; j < 16; ++j) ssum += vb[j];
        }
        ws[OFF_VSUM + unit * 64 + d] = ssum;
    }
}

// ---------------------------------------------------------------------------
// Kernel B: part 1 (blocks < 16): top-45 of M per (b,h).
//   Fast argmax round: DPP row-max (VALU) + 2 shfl + ballot/ffs; block merge
//   via parity-double-buffered LDS -> ONE barrier per round.
//   Lowest-index tie-break preserved (lane order == index order).
//           part 2 (blocks >= 16): cumsum write, 16 loads in flight
// ---------------------------------------------------------------------------
__global__ __launch_bounds__(256) void kB(const float* __restrict__ V,
                                          float* __restrict__ out,
                                          float* __restrict__ ws)
{
    int tid = threadIdx.x;

    if (blockIdx.x < 16) {
        int bh = blockIdx.x;
        const float* M = ws + OFF_M + (long)bh * L_;
        int* Mtop = (int*)ws + OFF_MTOP + bh * NT_;

        float vals[16];
#pragma unroll
        for (int j = 0; j < 16; ++j) vals[j] = M[tid * 16 + j];
        float lv = NEG_BIG; int li = tid * 16;
#pragma unroll
        for (int j = 0; j < 16; ++j) {
            if (vals[j] > lv) { lv = vals[j]; li = tid * 16 + j; }
        }

        __shared__ float wbv[2][4];
        __shared__ int   wbi[2][4];
        int lane = tid & 63, w = tid >> 6;

        for (int r = 0; r < NT_; ++r) {
            int par = r & 1;
            // wave max (value only): DPP row-max then 2 cross-row shfl
            float rm = lv;
            rm = fmaxf(rm, dpp_ror_f<0x121>(rm));
            rm = fmaxf(rm, dpp_ror_f<0x122>(rm));
            rm = fmaxf(rm, dpp_ror_f<0x124>(rm));
            rm = fmaxf(rm, dpp_ror_f<0x128>(rm));    // row (16-lane) max
            rm = fmaxf(rm, __shfl_xor(rm, 16));
            float wmax = fmaxf(rm, __shfl_xor(rm, 32));
            // lowest matching lane == lowest index (disjoint increasing ranges)
            unsigned long long bm = __ballot(lv == wmax);
            int winner = __ffsll((unsigned long long)bm) - 1;
            int wi = __shfl(li, winner);
            if (lane == 0) { wbv[par][w] = wmax; wbi[par][w] = wi; }
            __syncthreads();
            float bv = wbv[par][0]; int bi = wbi[par][0];
#pragma unroll
            for (int g = 1; g < 4; ++g) {
                float v2 = wbv[par][g]; int i2 = wbi[par][g];
                if (v2 > bv || (v2 == bv && i2 < bi)) { bv = v2; bi = i2; }
            }
            if (tid == 0) Mtop[r] = bi;
            if ((bi >> 4) == tid) {
#pragma unroll
                for (int j = 0; j < 16; ++j)
                    if (j == (bi & 15)) vals[j] = NEG_BIG;
                lv = NEG_BIG; li = tid * 16;
#pragma unroll
                for (int j = 0; j < 16; ++j)
                    if (vals[j] > lv) { lv = vals[j]; li = tid * 16 + j; }
            }
            // no second barrier: next round writes the other parity slot
        }
    } else {
        // wave per (bh, ch): inclusive scan within chunk, offset from vsum
        int w = tid >> 6, d = tid & 63;
        int unit = (blockIdx.x - 16) * 4 + w;    // 0..1023
        int bh = unit >> 6, ch = unit & 63;
        int b = bh >> 3, h = bh & 7;

        // prefix over earlier chunk sums, 8 loads in flight
        float acc = 0.f;
        {
            const float* vs = ws + OFF_VSUM + (long)bh * NCHV * 64 + d;
            int c = 0;
            for (; c + 8 <= ch; c += 8) {
                float vb[8];
#pragma unroll
                for (int j = 0; j < 8; ++j) vb[j] = vs[(c + j) * 64];
#pragma unroll
                for (int j = 0; j < 8; ++j) acc += vb[j];
            }
            for (; c < ch; ++c) acc += vs[c * 64];
        }

        const float* vp = V   + ((((long)b * L_ + (long)ch * CHV) * H_ + h) << 6) + d;
        float*       op = out + ((((long)b * L_ + (long)ch * CHV) * H_ + h) << 6) + d;
#pragma unroll
        for (int ib = 0; ib < CHV; ib += 16) {
            float vb[16];
#pragma unroll
            for (int j = 0; j < 16; ++j) vb[j] = vp[(long)(ib + j) * (H_ * D_)];
#pragma unroll
            for (int j = 0; j < 16; ++j) {
                acc += vb[j];
                op[(long)(ib + j) * (H_ * D_)] = acc;
            }
        }
    }
}

// ---------------------------------------------------------------------------
// Kernel C: attention partials. Block = (bh, kc, ug): ~23 selected queries
// (u-half ug) vs one 128-key chunk -> 1024 blocks (4/CU grid, 3/CU by LDS).
// K chunk staged coalesced into padded LDS (stride 68: measured 0 bank
// conflicts); P = 23x128 in LDS. LDS ~46.7 KB -> 3 blocks/CU.
// ---------------------------------------------------------------------------
#define KPAD 68
#define NUH  23   // max queries per block (ug=0: 23, ug=1: 22)
__global__ __launch_bounds__(256, 3) void kC(const float* __restrict__ Q,
                                             const float* __restrict__ Kt,
                                             const float* __restrict__ V,
                                             float* __restrict__ ws)
{
    __shared__ float Klds[KC * KPAD];  // 34816 B
    __shared__ float P[NUH * KC];      // 11776 B (scores -> exp weights)
    __shared__ int   qpos[NUH];

    int tid = threadIdx.x;
    int bh = blockIdx.x >> 6;
    int kc = (blockIdx.x >> 1) & 31;
    int ug = blockIdx.x & 1;
    int b = bh >> 3, h = bh & 7;
    int kbase = kc * KC;
    int u0 = ug * 23;
    int NU = ug ? 22 : 23;             // u in [u0, u0+NU)

    if (tid < NU) qpos[tid] = ((const int*)ws)[OFF_MTOP + bh * NT_ + u0 + tid];

    // coalesced K-chunk staging: 4 rows x 256B per iteration
    {
        const float* ksrc = Kt + ((((long)b * L_ + kbase) * H_ + h) << 6);
#pragma unroll
        for (int i = 0; i < 32; ++i) {
            int e = i * 256 + tid;
            int r = e >> 6, d = e & 63;
            Klds[r * KPAD + d] = ksrc[(long)r * (H_ * D_) + d];
        }
    }
    __syncthreads();

    // QK: thread = (k, u-quarter uh in {0,1}); K row from LDS into 64 VGPRs,
    // Q rows uniform loads (L1). 12 fixed trips (clamped dup: benign
    // same-thread rewrite). 4-way split accumulators (chain 64 -> 16).
    int k = tid & 127, uh = tid >> 7;
    int kpos = kbase + k;
    {
        float4 krow[16];
#pragma unroll
        for (int j = 0; j < 16; ++j)
            krow[j] = *(const float4*)&Klds[k * KPAD + j * 4];

#pragma unroll 2
        for (int j = 0; j < 12; ++j) {
            int ul = uh * 12 + j;
            if (ul > NU - 1) ul = NU - 1;          // clamp (dup write, same val)
            int qp_ = qpos[ul];
            const float4* qrow = (const float4*)(Q + ((((long)b * L_ + qp_) * H_ + h) << 6));
            float a0 = 0.f, a1 = 0.f, a2 = 0.f, a3 = 0.f;
#pragma unroll
            for (int jj = 0; jj < 16; jj += 4) {
                float4 q0 = qrow[jj + 0], q1 = qrow[jj + 1];
                float4 q2 = qrow[jj + 2], q3 = qrow[jj + 3];
                a0 += q0.x * krow[jj + 0].x + q0.y * krow[jj + 0].y +
                      q0.z * krow[jj + 0].z + q0.w * krow[jj + 0].w;
                a1 += q1.x * krow[jj + 1].x + q1.y * krow[jj + 1].y +
                      q1.z * krow[jj + 1].z + q1.w * krow[jj + 1].w;
                a2 += q2.x * krow[jj + 2].x + q2.y * krow[jj + 2].y +
                      q2.z * krow[jj + 2].z + q2.w * krow[jj + 2].w;
                a3 += q3.x * krow[jj + 3].x + q3.y * krow[jj + 3].y +
                      q3.z * krow[jj + 3].z + q3.w * krow[jj + 3].w;
            }
            float sc = ((a0 + a1) + (a2 + a3)) * SCALE;
            if (kpos > qp_) sc = NEG_BIG;   // causal mask
            P[ul * KC + k] = sc;
        }
    }
    __syncthreads();

    // per-u softmax partials (wave w handles ul = w, w+4, ...)
    int lane = tid & 63, w = tid >> 6;
    for (int ul = w; ul < NU; ul += 4) {
        float s0 = P[ul * KC + lane];
        float s1 = P[ul * KC + 64 + lane];
        float m = fmaxf(s0, s1);
#pragma unroll
        for (int off = 32; off; off >>= 1) m = fmaxf(m, __shfl_xor(m, off));
        float e0 = __expf(s0 - m), e1 = __expf(s1 - m);
        P[ul * KC + lane]      = e0;
        P[ul * KC + 64 + lane] = e1;
        float sm = e0 + e1;
#pragma unroll
        for (int off = 32; off; off >>= 1) sm += __shfl_xor(sm, off);
        if (lane == 0) {
            ws[OFF_MPART + ((long)bh * NT_ + u0 + ul) * NKC + kc] = m;
            ws[OFF_SPART + ((long)bh * NT_ + u0 + ul) * NKC + kc] = sm;
        }
    }
    __syncthreads();

    // PV: wave w accumulates ctx for ul in {w, w+4, ...} (<=6); lane = d.
    // V from global (coalesced 256B/instr, L1/L2-hot); P broadcast float4.
    {
        const float* vsrc = V + ((((long)b * L_ + kbase) * H_ + h) << 6);
        float ctx[6];
#pragma unroll
        for (int j = 0; j < 6; ++j) ctx[j] = 0.f;
        for (int kk = 0; kk < KC; kk += 4) {
            float v0 = vsrc[(long)(kk + 0) * (H_ * D_) + lane];
            float v1 = vsrc[(long)(kk + 1) * (H_ * D_) + lane];
            float v2 = vsrc[(long)(kk + 2) * (H_ * D_) + lane];
            float v3 = vsrc[(long)(kk + 3) * (H_ * D_) + lane];
#pragma unroll
            for (int j = 0; j < 6; ++j) {
                int ul = w + j * 4;
                if (ul < NU) {
                    float4 pv = *(const float4*)&P[ul * KC + kk];  // broadcast
                    ctx[j] += pv.x * v0 + pv.y * v1 + pv.z * v2 + pv.w * v3;
                }
            }
        }
#pragma unroll
        for (int j = 0; j < 6; ++j) {
            int ul = w + j * 4;
            if (ul < NU)
                ws[OFF_CTXP + ((long)(bh * NKC + kc) * NT_ + u0 + ul) * 64 + lane] = ctx[j];
        }
    }
}

// ---------------------------------------------------------------------------
// Kernel D: merge chunk partials (log-sum-exp) and overwrite selected rows.
// MPART/SPART are [bh][u][kc] -> float4 merge loads.
// ---------------------------------------------------------------------------
__global__ __launch_bounds__(256) void kD(float* __restrict__ out,
                                          const float* __restrict__ ws)
{
    int tid  = threadIdx.x;
    int w    = tid >> 6;
    int lane = tid & 63;
    int unit = blockIdx.x * 4 + w;       // 0..719
    if (unit >= BH_ * NT_) return;
    int bh = unit / NT_, u = unit - bh * NT_;
    int b = bh >> 3, h = bh & 7;

    const float4* mp4 = (const float4*)(ws + OFF_MPART + ((long)bh * NT_ + u) * NKC);
    const float4* sp4 = (const float4*)(ws + OFF_SPART + ((long)bh * NT_ + u) * NKC);

    float mc[NKC], sc[NKC];
    float m = NEG_BIG;
#pragma unroll
    for (int c4 = 0; c4 < NKC / 4; ++c4) {
        float4 mv = mp4[c4];
        float4 sv = sp4[c4];
        mc[c4 * 4 + 0] = mv.x; mc[c4 * 4 + 1] = mv.y;
        mc[c4 * 4 + 2] = mv.z; mc[c4 * 4 + 3] = mv.w;
        sc[c4 * 4 + 0] = sv.x; sc[c4 * 4 + 1] = sv.y;
        sc[c4 * 4 + 2] = sv.z; sc[c4 * 4 + 3] = sv.w;
        m = fmaxf(m, fmaxf(fmaxf(mv.x, mv.y), fmaxf(mv.z, mv.w)));
    }
    float T = 0.f, ctx = 0.f;
#pragma unroll
    for (int c = 0; c < NKC; ++c) {
        float wgt = __expf(mc[c] - m);   // fully-masked chunks: exp(-1e30-m) = 0
        T   += sc[c] * wgt;
        ctx += ws[OFF_CTXP + ((long)(bh * NKC + c) * NT_ + u) * 64 + lane] * wgt;
    }
    int qp = ((const int*)ws)[OFF_MTOP + bh * NT_ + u];
    out[((((long)b * L_ + qp) * H_ + h) << 6) + lane] = ctx / T;
}

// ---------------------------------------------------------------------------
extern "C" void kernel_launch(void* const* d_in, const int* in_sizes, int n_in,
                              void* d_out, int out_size, void* d_ws, size_t ws_size,
                              hipStream_t stream)
{
    const float* Q    = (const float*)d_in[0];
    const float* K    = (const float*)d_in[1];
    const float* V    = (const float*)d_in[2];
    const int*   samp = (const int*)d_in[4];   // d_in[3] = attn_mask (unused)
    float* out = (float*)d_out;
    float* ws  = (float*)d_ws;

    // A: M scores (16384 blocks = (b,q,hh), XCD-slab swizzled) + V chunk
    //    sums (512 blocks x 2 waves)
    kA<<<16896, 128, 0, stream>>>(Q, K, V, samp, ws);
    // B: top-45 (16 blocks) + cumsum write (256 blocks)
    kB<<<272, 256, 0, stream>>>(V, out, ws);
    // C: attention partials (16 bh x 32 key chunks x 2 u-halves)
    kC<<<1024, 256, 0, stream>>>(Q, K, V, ws);
    // D: merge + scatter selected rows (720 waves)
    kD<<<180, 256, 0, stream>>>(out, ws);
}

// Round 6
// 229.893 us; speedup vs baseline: 1.2040x; 1.2040x over previous
//
#include <hip/hip_runtime.h>
#include <math.h>

// Problem constants (fixed by setup_inputs)
#define B_    2
#define L_    4096
#define H_    8
#define D_    64
#define S_    45      // sample_k
#define NT_   45      // n_top
#define BH_   16      // B*H
#define CHV   64      // cumsum chunk length
#define NCHV  64      // L_/CHV
#define KC    128     // attention key-chunk length
#define NKC   32      // L_/KC
#define SCALE 0.125f  // 1/sqrt(64)
#define NEG_BIG (-1e30f)

// Workspace layout (float element offsets; ints share the same 4B slots).
// VSUM is only live between kA and kB-part2; CTXP is written in kC, so
// VSUM overlays the start of the CTXP region. Total ~6.35 MB (proven size).
#define OFF_M     0         // 65536 floats: M[bh][q]
#define OFF_MTOP  65536     // 720 ints:    M_top[bh][u]
#define OFF_MPART 66304     // 23040 floats: m partial [bh][u][kc]
#define OFF_SPART 89344     // 23040 floats: sumexp partial [bh][u][kc]
#define OFF_CTXP  112384    // 1474560 floats: ctx partial [bh][kc][u][d]
#define OFF_VSUM  112384    // 65536 floats: vsum[bh][ch][d] (overlays CTXP)

// DPP row-rotate combine: rotations by 1,2,4,8 within a 16-lane row.
// VALU-pipe (no ds_swizzle), full-rate. All lanes/masks enabled -> old unused.
template <int CTRL>
__device__ __forceinline__ float dpp_ror_f(float x) {
    int y = __builtin_amdgcn_update_dpp(0, __float_as_int(x), CTRL, 0xF, 0xF, false);
    return __int_as_float(y);
}

// ---------------------------------------------------------------------------
// Kernel A: part 1 (blocks < 16384): block = (b, q, hh) with 128 threads.
//   XCD-slab swizzle: blockIdx%8 = XCD (round-robin dispatch); slab
//   (b,hh) = 4096 rows x 1KB = 4MB = one XCD's L2.
//   Per sample one coalesced 1KB load covers 4 heads (lane = 16B chunk);
//   dot4 + 4-step DPP row-rotate reduce in 16-lane head groups.
//           part 2 (blocks >= 16384): per-chunk V sums, 16 loads in flight.
// ---------------------------------------------------------------------------
__global__ __launch_bounds__(128) void kA(const float* __restrict__ Q,
                                          const float* __restrict__ Kt,
                                          const float* __restrict__ V,
                                          const int* __restrict__ samp,
                                          float* __restrict__ ws)
{
    int tid  = threadIdx.x;
    int w    = tid >> 6;          // 0..1
    int lane = tid & 63;

    if (blockIdx.x < 16384) {
        // i%8 = XCD; slab = xcd>>1 in [0,4): b = slab>>1, hh = slab&1
        int i   = blockIdx.x;
        int xcd = i & 7;
        int b   = xcd >> 2;
        int hh  = (xcd >> 1) & 1;
        int q   = ((i >> 3) << 1) | (xcd & 1);   // 2048 j-slots x 2 = 4096 q

        __shared__ int   sidx[S_];
        __shared__ float redm[4][2], reds[4][2];

        if (tid < S_) sidx[tid] = samp[q * S_ + tid];
        __syncthreads();

        int sh = w;                   // sample-half
        int h4 = lane >> 4;           // head within half
        int h  = hh * 4 + h4;

        const float4 q4 = *(const float4*)(Q +
            ((((long)b * L_ + q) * H_ + hh * 4) << 6) + lane * 4);

        const float* kb_base = Kt + (((long)b * L_ * H_ + hh * 4) << 6) + lane * 4;

        // sh=0 covers s=0..22, sh=1 covers s=22..44 (s=22 dup: max-safe,
        // masked out of the sum). 24 trips (last clamped), 12-deep batches.
        float mx = NEG_BIG, sm = 0.f;
#pragma unroll
        for (int jb = 0; jb < 24; jb += 12) {
            float4 kb[12];
#pragma unroll
            for (int j = 0; j < 12; ++j) {
                int jj = jb + j;
                int jc = jj < 23 ? jj : 22;            // clamp 24th trip
                int s  = sh * 22 + jc;
                kb[j] = *(const float4*)(kb_base + (((long)sidx[s] * H_) << 6));
            }
#pragma unroll
            for (int j = 0; j < 12; ++j) {
                int jj = jb + j;
                float p = q4.x * kb[j].x + q4.y * kb[j].y +
                          q4.z * kb[j].z + q4.w * kb[j].w;
                p += dpp_ror_f<0x121>(p);   // ror 1
                p += dpp_ror_f<0x122>(p);   // ror 2
                p += dpp_ror_f<0x124>(p);   // ror 4
                p += dpp_ror_f<0x128>(p);   // ror 8 -> row sum (16 lanes)
                mx = fmaxf(mx, p);          // duplicates harmless for max
                bool valid = (jj < 23) && !(sh == 1 && jj == 0);
                sm += valid ? p : 0.f;
            }
        }
        if ((lane & 15) == 0) { redm[h4][sh] = mx; reds[h4][sh] = sm; }
        __syncthreads();
        if (tid < 4) {
            float m = fmaxf(redm[tid][0], redm[tid][1]);
            float s = reds[tid][0] + reds[tid][1];
            ws[OFF_M + ((long)(b * 8 + hh * 4 + tid)) * L_ + q] = m - s * (1.0f / (float)L_);
        }
    } else {
        // wave per (bh, ch): vsum[bh][ch][d] = sum_{i<CHV} V[b, ch*CHV+i, h, d]
        int unit = (blockIdx.x - 16384) * 2 + w;   // 0..1023
        int bh = unit >> 6, ch = unit & 63;
        int b = bh >> 3, h = bh & 7;
        int d = lane;
        const float* vp = V + ((((long)b * L_ + (long)ch * CHV) * H_ + h) << 6) + d;
        float ssum = 0.f;
#pragma unroll
        for (int ib = 0; ib < CHV; ib += 16) {
            float vb[16];
#pragma unroll
            for (int j = 0; j < 16; ++j) vb[j] = vp[(long)(ib + j) * (H_ * D_)];
#pragma unroll
            for (int j = 0; j < 16; ++j) ssum += vb[j];
        }
        ws[OFF_VSUM + unit * 64 + d] = ssum;
    }
}

// ---------------------------------------------------------------------------
// Kernel B: part 1 (blocks < 16): top-45 of M per (b,h).
//   Fast argmax round: DPP row-max (VALU) + 2 shfl + ballot/ffs; block merge
//   via parity-double-buffered LDS -> ONE barrier per round.
//   Lowest-index tie-break preserved (lane order == index order).
//           part 2 (blocks >= 16): cumsum write, 16 loads in flight
// ---------------------------------------------------------------------------
__global__ __launch_bounds__(256) void kB(const float* __restrict__ V,
                                          float* __restrict__ out,
                                          float* __restrict__ ws)
{
    int tid = threadIdx.x;

    if (blockIdx.x < 16) {
        int bh = blockIdx.x;
        const float* M = ws + OFF_M + (long)bh * L_;
        int* Mtop = (int*)ws + OFF_MTOP + bh * NT_;

        float vals[16];
#pragma unroll
        for (int j = 0; j < 16; ++j) vals[j] = M[tid * 16 + j];
        float lv = NEG_BIG; int li = tid * 16;
#pragma unroll
        for (int j = 0; j < 16; ++j) {
            if (vals[j] > lv) { lv = vals[j]; li = tid * 16 + j; }
        }

        __shared__ float wbv[2][4];
        __shared__ int   wbi[2][4];
        int lane = tid & 63, w = tid >> 6;

        for (int r = 0; r < NT_; ++r) {
            int par = r & 1;
            // wave max (value only): DPP row-max then 2 cross-row shfl
            float rm = lv;
            rm = fmaxf(rm, dpp_ror_f<0x121>(rm));
            rm = fmaxf(rm, dpp_ror_f<0x122>(rm));
            rm = fmaxf(rm, dpp_ror_f<0x124>(rm));
            rm = fmaxf(rm, dpp_ror_f<0x128>(rm));    // row (16-lane) max
            rm = fmaxf(rm, __shfl_xor(rm, 16));
            float wmax = fmaxf(rm, __shfl_xor(rm, 32));
            // lowest matching lane == lowest index (disjoint increasing ranges)
            unsigned long long bm = __ballot(lv == wmax);
            int winner = __ffsll((unsigned long long)bm) - 1;
            int wi = __shfl(li, winner);
            if (lane == 0) { wbv[par][w] = wmax; wbi[par][w] = wi; }
            __syncthreads();
            float bv = wbv[par][0]; int bi = wbi[par][0];
#pragma unroll
            for (int g = 1; g < 4; ++g) {
                float v2 = wbv[par][g]; int i2 = wbi[par][g];
                if (v2 > bv || (v2 == bv && i2 < bi)) { bv = v2; bi = i2; }
            }
            if (tid == 0) Mtop[r] = bi;
            if ((bi >> 4) == tid) {
#pragma unroll
                for (int j = 0; j < 16; ++j)
                    if (j == (bi & 15)) vals[j] = NEG_BIG;
                lv = NEG_BIG; li = tid * 16;
#pragma unroll
                for (int j = 0; j < 16; ++j)
                    if (vals[j] > lv) { lv = vals[j]; li = tid * 16 + j; }
            }
            // no second barrier: next round writes the other parity slot
        }
    } else {
        // wave per (bh, ch): inclusive scan within chunk, offset from vsum
        int w = tid >> 6, d = tid & 63;
        int unit = (blockIdx.x - 16) * 4 + w;    // 0..1023
        int bh = unit >> 6, ch = unit & 63;
        int b = bh >> 3, h = bh & 7;

        // prefix over earlier chunk sums, 8 loads in flight
        float acc = 0.f;
        {
            const float* vs = ws + OFF_VSUM + (long)bh * NCHV * 64 + d;
            int c = 0;
            for (; c + 8 <= ch; c += 8) {
                float vb[8];
#pragma unroll
                for (int j = 0; j < 8; ++j) vb[j] = vs[(c + j) * 64];
#pragma unroll
                for (int j = 0; j < 8; ++j) acc += vb[j];
            }
            for (; c < ch; ++c) acc += vs[c * 64];
        }

        const float* vp = V   + ((((long)b * L_ + (long)ch * CHV) * H_ + h) << 6) + d;
        float*       op = out + ((((long)b * L_ + (long)ch * CHV) * H_ + h) << 6) + d;
#pragma unroll
        for (int ib = 0; ib < CHV; ib += 16) {
            float vb[16];
#pragma unroll
            for (int j = 0; j < 16; ++j) vb[j] = vp[(long)(ib + j) * (H_ * D_)];
#pragma unroll
            for (int j = 0; j < 16; ++j) {
                acc += vb[j];
                op[(long)(ib + j) * (H_ * D_)] = acc;
            }
        }
    }
}

// ---------------------------------------------------------------------------
// Kernel C: attention partials. Block = (bh, kc, ug): ~23 selected queries
// (u-half ug) vs one 128-key chunk -> 1024 blocks. LDS ~46.7 KB -> 3
// blocks/CU. NO min-waves launch bound: forcing 3 waves/EU in R5 capped
// VGPR at 84 -> krow spilled to scratch (92 MB writes, 135 us). Natural
// allocation (~128 VGPR) still permits 3 waves/EU without spilling.
// ---------------------------------------------------------------------------
#define KPAD 68
#define NUH  23   // max queries per block (ug=0: 23, ug=1: 22)
__global__ __launch_bounds__(256) void kC(const float* __restrict__ Q,
                                          const float* __restrict__ Kt,
                                          const float* __restrict__ V,
                                          float* __restrict__ ws)
{
    __shared__ float Klds[KC * KPAD];  // 34816 B
    __shared__ float P[NUH * KC];      // 11776 B (scores -> exp weights)
    __shared__ int   qpos[NUH];

    int tid = threadIdx.x;
    int bh = blockIdx.x >> 6;
    int kc = (blockIdx.x >> 1) & 31;
    int ug = blockIdx.x & 1;
    int b = bh >> 3, h = bh & 7;
    int kbase = kc * KC;
    int u0 = ug * 23;
    int NU = ug ? 22 : 23;             // u in [u0, u0+NU)

    if (tid < NU) qpos[tid] = ((const int*)ws)[OFF_MTOP + bh * NT_ + u0 + tid];

    // coalesced K-chunk staging: 4 rows x 256B per iteration
    {
        const float* ksrc = Kt + ((((long)b * L_ + kbase) * H_ + h) << 6);
#pragma unroll
        for (int i = 0; i < 32; ++i) {
            int e = i * 256 + tid;
            int r = e >> 6, d = e & 63;
            Klds[r * KPAD + d] = ksrc[(long)r * (H_ * D_) + d];
        }
    }
    __syncthreads();

    // QK: thread = (k, u-quarter uh in {0,1}); K row from LDS into 64 VGPRs,
    // Q rows uniform loads (L1). 12 fixed trips (clamped dup: benign
    // same-thread rewrite). 4-way split accumulators (chain 64 -> 16).
    int k = tid & 127, uh = tid >> 7;
    int kpos = kbase + k;
    {
        float4 krow[16];
#pragma unroll
        for (int j = 0; j < 16; ++j)
            krow[j] = *(const float4*)&Klds[k * KPAD + j * 4];

#pragma unroll 2
        for (int j = 0; j < 12; ++j) {
            int ul = uh * 12 + j;
            if (ul > NU - 1) ul = NU - 1;          // clamp (dup write, same val)
            int qp_ = qpos[ul];
            const float4* qrow = (const float4*)(Q + ((((long)b * L_ + qp_) * H_ + h) << 6));
            float a0 = 0.f, a1 = 0.f, a2 = 0.f, a3 = 0.f;
#pragma unroll
            for (int jj = 0; jj < 16; jj += 4) {
                float4 q0 = qrow[jj + 0], q1 = qrow[jj + 1];
                float4 q2 = qrow[jj + 2], q3 = qrow[jj + 3];
                a0 += q0.x * krow[jj + 0].x + q0.y * krow[jj + 0].y +
                      q0.z * krow[jj + 0].z + q0.w * krow[jj + 0].w;
                a1 += q1.x * krow[jj + 1].x + q1.y * krow[jj + 1].y +
                      q1.z * krow[jj + 1].z + q1.w * krow[jj + 1].w;
                a2 += q2.x * krow[jj + 2].x + q2.y * krow[jj + 2].y +
                      q2.z * krow[jj + 2].z + q2.w * krow[jj + 2].w;
                a3 += q3.x * krow[jj + 3].x + q3.y * krow[jj + 3].y +
                      q3.z * krow[jj + 3].z + q3.w * krow[jj + 3].w;
            }
            float sc = ((a0 + a1) + (a2 + a3)) * SCALE;
            if (kpos > qp_) sc = NEG_BIG;   // causal mask
            P[ul * KC + k] = sc;
        }
    }
    __syncthreads();

    // per-u softmax partials (wave w handles ul = w, w+4, ...)
    int lane = tid & 63, w = tid >> 6;
    for (int ul = w; ul < NU; ul += 4) {
        float s0 = P[ul * KC + lane];
        float s1 = P[ul * KC + 64 + lane];
        float m = fmaxf(s0, s1);
#pragma unroll
        for (int off = 32; off; off >>= 1) m = fmaxf(m, __shfl_xor(m, off));
        float e0 = __expf(s0 - m), e1 = __expf(s1 - m);
        P[ul * KC + lane]      = e0;
        P[ul * KC + 64 + lane] = e1;
        float sm = e0 + e1;
#pragma unroll
        for (int off = 32; off; off >>= 1) sm += __shfl_xor(sm, off);
        if (lane == 0) {
            ws[OFF_MPART + ((long)bh * NT_ + u0 + ul) * NKC + kc] = m;
            ws[OFF_SPART + ((long)bh * NT_ + u0 + ul) * NKC + kc] = sm;
        }
    }
    __syncthreads();

    // PV: wave w accumulates ctx for ul in {w, w+4, ...} (<=6); lane = d.
    // V from global (coalesced 256B/instr, L1/L2-hot); P broadcast float4.
    {
        const float* vsrc = V + ((((long)b * L_ + kbase) * H_ + h) << 6);
        float ctx[6];
#pragma unroll
        for (int j = 0; j < 6; ++j) ctx[j] = 0.f;
        for (int kk = 0; kk < KC; kk += 4) {
            float v0 = vsrc[(long)(kk + 0) * (H_ * D_) + lane];
            float v1 = vsrc[(long)(kk + 1) * (H_ * D_) + lane];
            float v2 = vsrc[(long)(kk + 2) * (H_ * D_) + lane];
            float v3 = vsrc[(long)(kk + 3) * (H_ * D_) + lane];
#pragma unroll
            for (int j = 0; j < 6; ++j) {
                int ul = w + j * 4;
                if (ul < NU) {
                    float4 pv = *(const float4*)&P[ul * KC + kk];  // broadcast
                    ctx[j] += pv.x * v0 + pv.y * v1 + pv.z * v2 + pv.w * v3;
                }
            }
        }
#pragma unroll
        for (int j = 0; j < 6; ++j) {
            int ul = w + j * 4;
            if (ul < NU)
                ws[OFF_CTXP + ((long)(bh * NKC + kc) * NT_ + u0 + ul) * 64 + lane] = ctx[j];
        }
    }
}

// ---------------------------------------------------------------------------
// Kernel D: merge chunk partials (log-sum-exp) and overwrite selected rows.
// MPART/SPART are [bh][u][kc] -> float4 merge loads.
// ---------------------------------------------------------------------------
__global__ __launch_bounds__(256) void kD(float* __restrict__ out,
                                          const float* __restrict__ ws)
{
    int tid  = threadIdx.x;
    int w    = tid >> 6;
    int lane = tid & 63;
    int unit = blockIdx.x * 4 + w;       // 0..719
    if (unit >= BH_ * NT_) return;
    int bh = unit / NT_, u = unit - bh * NT_;
    int b = bh >> 3, h = bh & 7;

    const float4* mp4 = (const float4*)(ws + OFF_MPART + ((long)bh * NT_ + u) * NKC);
    const float4* sp4 = (const float4*)(ws + OFF_SPART + ((long)bh * NT_ + u) * NKC);

    float mc[NKC], sc[NKC];
    float m = NEG_BIG;
#pragma unroll
    for (int c4 = 0; c4 < NKC / 4; ++c4) {
        float4 mv = mp4[c4];
        float4 sv = sp4[c4];
        mc[c4 * 4 + 0] = mv.x; mc[c4 * 4 + 1] = mv.y;
        mc[c4 * 4 + 2] = mv.z; mc[c4 * 4 + 3] = mv.w;
        sc[c4 * 4 + 0] = sv.x; sc[c4 * 4 + 1] = sv.y;
        sc[c4 * 4 + 2] = sv.z; sc[c4 * 4 + 3] = sv.w;
        m = fmaxf(m, fmaxf(fmaxf(mv.x, mv.y), fmaxf(mv.z, mv.w)));
    }
    float T = 0.f, ctx = 0.f;
#pragma unroll
    for (int c = 0; c < NKC; ++c) {
        float wgt = __expf(mc[c] - m);   // fully-masked chunks: exp(-1e30-m) = 0
        T   += sc[c] * wgt;
        ctx += ws[OFF_CTXP + ((long)(bh * NKC + c) * NT_ + u) * 64 + lane] * wgt;
    }
    int qp = ((const int*)ws)[OFF_MTOP + bh * NT_ + u];
    out[((((long)b * L_ + qp) * H_ + h) << 6) + lane] = ctx / T;
}

// ---------------------------------------------------------------------------
extern "C" void kernel_launch(void* const* d_in, const int* in_sizes, int n_in,
                              void* d_out, int out_size, void* d_ws, size_t ws_size,
                              hipStream_t stream)
{
    const float* Q    = (const float*)d_in[0];
    const float* K    = (const float*)d_in[1];
    const float* V    = (const float*)d_in[2];
    const int*   samp = (const int*)d_in[4];   // d_in[3] = attn_mask (unused)
    float* out = (float*)d_out;
    float* ws  = (float*)d_ws;

    // A: M scores (16384 blocks = (b,q,hh), XCD-slab swizzled) + V chunk
    //    sums (512 blocks x 2 waves)
    kA<<<16896, 128, 0, stream>>>(Q, K, V, samp, ws);
    // B: top-45 (16 blocks) + cumsum write (256 blocks)
    kB<<<272, 256, 0, stream>>>(V, out, ws);
    // C: attention partials (16 bh x 32 key chunks x 2 u-halves)
    kC<<<1024, 256, 0, stream>>>(Q, K, V, ws);
    // D: merge + scatter selected rows (720 waves)
    kD<<<180, 256, 0, stream>>>(out, ws);
}

// Round 7
// 193.070 us; speedup vs baseline: 1.4336x; 1.1907x over previous
//
#include <hip/hip_runtime.h>
#include <math.h>

// Problem constants (fixed by setup_inputs)
#define B_    2
#define L_    4096
#define H_    8
#define D_    64
#define S_    45      // sample_k
#define NT_   45      // n_top
#define BH_   16      // B*H
#define CHV   64      // cumsum chunk length
#define NCHV  64      // L_/CHV
#define KC    128     // attention key-chunk length
#define NKC   32      // L_/KC
#define SCALE 0.125f  // 1/sqrt(64)
#define NEG_BIG (-1e30f)

// Workspace layout (float element offsets; ints share the same 4B slots).
// VSUM is only live between kA and kB-part2; CTXP is written in kC, so
// VSUM overlays the start of the CTXP region. Total ~6.35 MB (proven size).
#define OFF_M     0         // 65536 floats: M[bh][q]
#define OFF_MTOP  65536     // 720 ints:    M_top[bh][u]
#define OFF_MPART 66304     // 23040 floats: m partial [bh][u][kc]
#define OFF_SPART 89344     // 23040 floats: sumexp partial [bh][u][kc]
#define OFF_CTXP  112384    // 1474560 floats: ctx partial [bh][kc][u][d]
#define OFF_VSUM  112384    // 65536 floats: vsum[bh][ch][d] (overlays CTXP)

// DPP row-rotate combine: rotations by 1,2,4,8 within a 16-lane row.
// VALU-pipe (no ds_swizzle), full-rate. All lanes/masks enabled -> old unused.
template <int CTRL>
__device__ __forceinline__ float dpp_ror_f(float x) {
    int y = __builtin_amdgcn_update_dpp(0, __float_as_int(x), CTRL, 0xF, 0xF, false);
    return __int_as_float(y);
}

// bf16 <-> f32 bit tricks (bf16 = high 16 bits of fp32; truncation rounding)
__device__ __forceinline__ unsigned short f2bf(float x) {
    return (unsigned short)(__float_as_uint(x) >> 16);
}
__device__ __forceinline__ float bflo(unsigned u) {   // low 16 bits -> f32
    return __uint_as_float(u << 16);
}
__device__ __forceinline__ float bfhi(unsigned u) {   // high 16 bits -> f32
    return __uint_as_float(u & 0xffff0000u);
}

// ---------------------------------------------------------------------------
// Kernel A: part 1 (blocks < 16384): block = (b, q, hh) with 128 threads.
//   XCD-slab swizzle: blockIdx%8 = XCD (round-robin dispatch); slab
//   (b,hh) = 4096 rows x 1KB = 4MB = one XCD's L2.
//   Per sample one coalesced 1KB load covers 4 heads (lane = 16B chunk);
//   dot4 + 4-step DPP row-rotate reduce in 16-lane head groups.
//           part 2 (blocks >= 16384): per-chunk V sums, 16 loads in flight.
// ---------------------------------------------------------------------------
__global__ __launch_bounds__(128) void kA(const float* __restrict__ Q,
                                          const float* __restrict__ Kt,
                                          const float* __restrict__ V,
                                          const int* __restrict__ samp,
                                          float* __restrict__ ws)
{
    int tid  = threadIdx.x;
    int w    = tid >> 6;          // 0..1
    int lane = tid & 63;

    if (blockIdx.x < 16384) {
        // i%8 = XCD; slab = xcd>>1 in [0,4): b = slab>>1, hh = slab&1
        int i   = blockIdx.x;
        int xcd = i & 7;
        int b   = xcd >> 2;
        int hh  = (xcd >> 1) & 1;
        int q   = ((i >> 3) << 1) | (xcd & 1);   // 2048 j-slots x 2 = 4096 q

        __shared__ int   sidx[S_];
        __shared__ float redm[4][2], reds[4][2];

        if (tid < S_) sidx[tid] = samp[q * S_ + tid];
        __syncthreads();

        int sh = w;                   // sample-half
        int h4 = lane >> 4;           // head within half
        int h  = hh * 4 + h4;

        const float4 q4 = *(const float4*)(Q +
            ((((long)b * L_ + q) * H_ + hh * 4) << 6) + lane * 4);

        const float* kb_base = Kt + (((long)b * L_ * H_ + hh * 4) << 6) + lane * 4;

        // sh=0 covers s=0..22, sh=1 covers s=22..44 (s=22 dup: max-safe,
        // masked out of the sum). 24 trips (last clamped), 12-deep batches.
        float mx = NEG_BIG, sm = 0.f;
#pragma unroll
        for (int jb = 0; jb < 24; jb += 12) {
            float4 kb[12];
#pragma unroll
            for (int j = 0; j < 12; ++j) {
                int jj = jb + j;
                int jc = jj < 23 ? jj : 22;            // clamp 24th trip
                int s  = sh * 22 + jc;
                kb[j] = *(const float4*)(kb_base + (((long)sidx[s] * H_) << 6));
            }
#pragma unroll
            for (int j = 0; j < 12; ++j) {
                int jj = jb + j;
                float p = q4.x * kb[j].x + q4.y * kb[j].y +
                          q4.z * kb[j].z + q4.w * kb[j].w;
                p += dpp_ror_f<0x121>(p);   // ror 1
                p += dpp_ror_f<0x122>(p);   // ror 2
                p += dpp_ror_f<0x124>(p);   // ror 4
                p += dpp_ror_f<0x128>(p);   // ror 8 -> row sum (16 lanes)
                mx = fmaxf(mx, p);          // duplicates harmless for max
                bool valid = (jj < 23) && !(sh == 1 && jj == 0);
                sm += valid ? p : 0.f;
            }
        }
        if ((lane & 15) == 0) { redm[h4][sh] = mx; reds[h4][sh] = sm; }
        __syncthreads();
        if (tid < 4) {
            float m = fmaxf(redm[tid][0], redm[tid][1]);
            float s = reds[tid][0] + reds[tid][1];
            ws[OFF_M + ((long)(b * 8 + hh * 4 + tid)) * L_ + q] = m - s * (1.0f / (float)L_);
        }
    } else {
        // wave per (bh, ch): vsum[bh][ch][d] = sum_{i<CHV} V[b, ch*CHV+i, h, d]
        int unit = (blockIdx.x - 16384) * 2 + w;   // 0..1023
        int bh = unit >> 6, ch = unit & 63;
        int b = bh >> 3, h = bh & 7;
        int d = lane;
        const float* vp = V + ((((long)b * L_ + (long)ch * CHV) * H_ + h) << 6) + d;
        float ssum = 0.f;
#pragma unroll
        for (int ib = 0; ib < CHV; ib += 16) {
            float vb[16];
#pragma unroll
            for (int j = 0; j < 16; ++j) vb[j] = vp[(long)(ib + j) * (H_ * D_)];
#pragma unroll
            for (int j = 0; j < 16; ++j) ssum += vb[j];
        }
        ws[OFF_VSUM + unit * 64 + d] = ssum;
    }
}

// ---------------------------------------------------------------------------
// Kernel B: part 1 (blocks < 16): top-45 of M per (b,h).
//   Fast argmax round: DPP row-max (VALU) + 2 shfl + ballot/ffs; block merge
//   via parity-double-buffered LDS -> ONE barrier per round.
//   Lowest-index tie-break preserved (lane order == index order).
//           part 2 (blocks >= 16): cumsum write, 16 loads in flight
// ---------------------------------------------------------------------------
__global__ __launch_bounds__(256) void kB(const float* __restrict__ V,
                                          float* __restrict__ out,
                                          float* __restrict__ ws)
{
    int tid = threadIdx.x;

    if (blockIdx.x < 16) {
        int bh = blockIdx.x;
        const float* M = ws + OFF_M + (long)bh * L_;
        int* Mtop = (int*)ws + OFF_MTOP + bh * NT_;

        float vals[16];
#pragma unroll
        for (int j = 0; j < 16; ++j) vals[j] = M[tid * 16 + j];
        float lv = NEG_BIG; int li = tid * 16;
#pragma unroll
        for (int j = 0; j < 16; ++j) {
            if (vals[j] > lv) { lv = vals[j]; li = tid * 16 + j; }
        }

        __shared__ float wbv[2][4];
        __shared__ int   wbi[2][4];
        int lane = tid & 63, w = tid >> 6;

        for (int r = 0; r < NT_; ++r) {
            int par = r & 1;
            // wave max (value only): DPP row-max then 2 cross-row shfl
            float rm = lv;
            rm = fmaxf(rm, dpp_ror_f<0x121>(rm));
            rm = fmaxf(rm, dpp_ror_f<0x122>(rm));
            rm = fmaxf(rm, dpp_ror_f<0x124>(rm));
            rm = fmaxf(rm, dpp_ror_f<0x128>(rm));    // row (16-lane) max
            rm = fmaxf(rm, __shfl_xor(rm, 16));
            float wmax = fmaxf(rm, __shfl_xor(rm, 32));
            // lowest matching lane == lowest index (disjoint increasing ranges)
            unsigned long long bm = __ballot(lv == wmax);
            int winner = __ffsll((unsigned long long)bm) - 1;
            int wi = __shfl(li, winner);
            if (lane == 0) { wbv[par][w] = wmax; wbi[par][w] = wi; }
            __syncthreads();
            float bv = wbv[par][0]; int bi = wbi[par][0];
#pragma unroll
            for (int g = 1; g < 4; ++g) {
                float v2 = wbv[par][g]; int i2 = wbi[par][g];
                if (v2 > bv || (v2 == bv && i2 < bi)) { bv = v2; bi = i2; }
            }
            if (tid == 0) Mtop[r] = bi;
            if ((bi >> 4) == tid) {
#pragma unroll
                for (int j = 0; j < 16; ++j)
                    if (j == (bi & 15)) vals[j] = NEG_BIG;
                lv = NEG_BIG; li = tid * 16;
#pragma unroll
                for (int j = 0; j < 16; ++j)
                    if (vals[j] > lv) { lv = vals[j]; li = tid * 16 + j; }
            }
            // no second barrier: next round writes the other parity slot
        }
    } else {
        // wave per (bh, ch): inclusive scan within chunk, offset from vsum
        int w = tid >> 6, d = tid & 63;
        int unit = (blockIdx.x - 16) * 4 + w;    // 0..1023
        int bh = unit >> 6, ch = unit & 63;
        int b = bh >> 3, h = bh & 7;

        // prefix over earlier chunk sums, 8 loads in flight
        float acc = 0.f;
        {
            const float* vs = ws + OFF_VSUM + (long)bh * NCHV * 64 + d;
            int c = 0;
            for (; c + 8 <= ch; c += 8) {
                float vb[8];
#pragma unroll
                for (int j = 0; j < 8; ++j) vb[j] = vs[(c + j) * 64];
#pragma unroll
                for (int j = 0; j < 8; ++j) acc += vb[j];
            }
            for (; c < ch; ++c) acc += vs[c * 64];
        }

        const float* vp = V   + ((((long)b * L_ + (long)ch * CHV) * H_ + h) << 6) + d;
        float*       op = out + ((((long)b * L_ + (long)ch * CHV) * H_ + h) << 6) + d;
#pragma unroll
        for (int ib = 0; ib < CHV; ib += 16) {
            float vb[16];
#pragma unroll
            for (int j = 0; j < 16; ++j) vb[j] = vp[(long)(ib + j) * (H_ * D_)];
#pragma unroll
            for (int j = 0; j < 16; ++j) {
                acc += vb[j];
                op[(long)(ib + j) * (H_ * D_)] = acc;
            }
        }
    }
}

// ---------------------------------------------------------------------------
// Kernel C: attention partials. Block = (bh, kc, ug): ~23 selected queries
// (u-half ug) vs one 128-key chunk -> 1024 blocks.
// K chunk + P stored as BF16 in LDS (scores/attn-weights only; top-k
// selection already fixed in kA/kB, error << threshold): LDS = 18.4 + 5.9
// = 24.4 KB -> no LDS occupancy cap (grid/VGPR-limited, ~16 waves/CU).
// Q rows loaded through readfirstlane-uniform base (single line request).
// PV reads P as 8-wide bf16 b128 -> half the LDS-pipe instructions.
// NO min-waves launch bound (R5 lesson: forcing it caused scratch spills).
// ---------------------------------------------------------------------------
#define KPAD16 72   // bf16 row stride: 144B, 16B-aligned, conflict-free quads
#define NUH    23   // max queries per block (ug=0: 23, ug=1: 22)
__global__ __launch_bounds__(256) void kC(const float* __restrict__ Q,
                                          const float* __restrict__ Kt,
                                          const float* __restrict__ V,
                                          float* __restrict__ ws)
{
    __shared__ unsigned short Klds16[KC * KPAD16];  // 18432 B
    __shared__ unsigned short P16[NUH * KC];        // 5888 B
    __shared__ int qpos[NUH];

    int tid = threadIdx.x;
    int bh = blockIdx.x >> 6;
    int kc = (blockIdx.x >> 1) & 31;
    int ug = blockIdx.x & 1;
    int b = bh >> 3, h = bh & 7;
    int kbase = kc * KC;
    int u0 = ug * 23;
    int NU = ug ? 22 : 23;             // u in [u0, u0+NU)

    if (tid < NU) qpos[tid] = ((const int*)ws)[OFF_MTOP + bh * NT_ + u0 + tid];

    // coalesced K-chunk staging: float4 global reads -> packed bf16 LDS
    {
        const float4* ksrc4 = (const float4*)(Kt + ((((long)b * L_ + kbase) * H_ + h) << 6));
#pragma unroll
        for (int i = 0; i < 8; ++i) {
            int e = i * 256 + tid;         // 0..2047 float4 slots
            int r = e >> 4, c4 = e & 15;   // row, float4-within-row
            float4 kv = ksrc4[(long)r * (H_ * D_ / 4) + c4];
            uint2 pk;
            pk.x = (__float_as_uint(kv.x) >> 16) | (__float_as_uint(kv.y) & 0xffff0000u);
            pk.y = (__float_as_uint(kv.z) >> 16) | (__float_as_uint(kv.w) & 0xffff0000u);
            *(uint2*)&Klds16[r * KPAD16 + c4 * 4] = pk;
        }
    }
    __syncthreads();

    // QK: thread = (k, uh in {0,1}); K row unpacked from LDS bf16 into 64
    // fp32 VGPRs once; Q rows via uniform (readfirstlane) base. Fixed 12
    // trips (clamped dup: benign same-thread rewrite). 4-way accumulators.
    int k = tid & 127, uh = tid >> 7;
    int kpos = kbase + k;
    {
        float kf[64];
#pragma unroll
        for (int j = 0; j < 8; ++j) {
            uint4 U = *(const uint4*)&Klds16[k * KPAD16 + j * 8];
            kf[j*8+0] = bflo(U.x); kf[j*8+1] = bfhi(U.x);
            kf[j*8+2] = bflo(U.y); kf[j*8+3] = bfhi(U.y);
            kf[j*8+4] = bflo(U.z); kf[j*8+5] = bfhi(U.z);
            kf[j*8+6] = bflo(U.w); kf[j*8+7] = bfhi(U.w);
        }

#pragma unroll 3
        for (int j = 0; j < 12; ++j) {
            int ul = uh * 12 + j;
            if (ul > NU - 1) ul = NU - 1;          // clamp (dup write, same val)
            int qp_ = __builtin_amdgcn_readfirstlane(qpos[ul]);
            const float4* qrow = (const float4*)(Q + ((((long)b * L_ + qp_) * H_ + h) << 6));
            float a0 = 0.f, a1 = 0.f, a2 = 0.f, a3 = 0.f;
#pragma unroll
            for (int jj = 0; jj < 16; jj += 4) {
                float4 q0 = qrow[jj + 0], q1 = qrow[jj + 1];
                float4 q2 = qrow[jj + 2], q3 = qrow[jj + 3];
                a0 += q0.x * kf[jj*4+ 0] + q0.y * kf[jj*4+ 1] +
                      q0.z * kf[jj*4+ 2] + q0.w * kf[jj*4+ 3];
                a1 += q1.x * kf[jj*4+ 4] + q1.y * kf[jj*4+ 5] +
                      q1.z * kf[jj*4+ 6] + q1.w * kf[jj*4+ 7];
                a2 += q2.x * kf[jj*4+ 8] + q2.y * kf[jj*4+ 9] +
                      q2.z * kf[jj*4+10] + q2.w * kf[jj*4+11];
                a3 += q3.x * kf[jj*4+12] + q3.y * kf[jj*4+13] +
                      q3.z * kf[jj*4+14] + q3.w * kf[jj*4+15];
            }
            float sc = ((a0 + a1) + (a2 + a3)) * SCALE;
            if (kpos > qp_) sc = NEG_BIG;   // causal mask
            P16[ul * KC + k] = f2bf(sc);
        }
    }
    __syncthreads();

    // per-u softmax partials (wave w handles ul = w, w+4, ...). Sum uses the
    // bf16-truncated e values so T matches what PV accumulates.
    int lane = tid & 63, w = tid >> 6;
    for (int ul = w; ul < NU; ul += 4) {
        float s0 = bflo(P16[ul * KC + lane]);
        float s1 = bflo(P16[ul * KC + 64 + lane]);
        float m = fmaxf(s0, s1);
#pragma unroll
        for (int off = 32; off; off >>= 1) m = fmaxf(m, __shfl_xor(m, off));
        float e0 = __expf(s0 - m), e1 = __expf(s1 - m);
        unsigned short b0 = f2bf(e0), b1 = f2bf(e1);
        P16[ul * KC + lane]      = b0;
        P16[ul * KC + 64 + lane] = b1;
        float sm = bflo(b0) + bflo(b1);
#pragma unroll
        for (int off = 32; off; off >>= 1) sm += __shfl_xor(sm, off);
        if (lane == 0) {
            ws[OFF_MPART + ((long)bh * NT_ + u0 + ul) * NKC + kc] = m;
            ws[OFF_SPART + ((long)bh * NT_ + u0 + ul) * NKC + kc] = sm;
        }
    }
    __syncthreads();

    // PV: wave w accumulates ctx for ul in {w, w+4, ...} (<=6); lane = d.
    // V from global (coalesced 256B/instr); P read as 8-wide bf16 b128
    // broadcast (one LDS instr per 8 MACs).
    {
        const float* vsrc = V + ((((long)b * L_ + kbase) * H_ + h) << 6);
        float ctx[6];
#pragma unroll
        for (int j = 0; j < 6; ++j) ctx[j] = 0.f;
        for (int kk8 = 0; kk8 < 16; ++kk8) {
            float v[8];
#pragma unroll
            for (int t = 0; t < 8; ++t)
                v[t] = vsrc[(long)(kk8 * 8 + t) * (H_ * D_) + lane];
#pragma unroll
            for (int j = 0; j < 6; ++j) {
                int ul = w + j * 4;
                if (ul < NU) {
                    uint4 U = *(const uint4*)&P16[ul * KC + kk8 * 8];  // broadcast
                    ctx[j] += bflo(U.x) * v[0] + bfhi(U.x) * v[1]
                            + bflo(U.y) * v[2] + bfhi(U.y) * v[3]
                            + bflo(U.z) * v[4] + bfhi(U.z) * v[5]
                            + bflo(U.w) * v[6] + bfhi(U.w) * v[7];
                }
            }
        }
#pragma unroll
        for (int j = 0; j < 6; ++j) {
            int ul = w + j * 4;
            if (ul < NU)
                ws[OFF_CTXP + ((long)(bh * NKC + kc) * NT_ + u0 + ul) * 64 + lane] = ctx[j];
        }
    }
}

// ---------------------------------------------------------------------------
// Kernel D: merge chunk partials (log-sum-exp) and overwrite selected rows.
// One 64-thread block per (bh,u) unit: 720 blocks (~2.8/CU).
// ---------------------------------------------------------------------------
__global__ __launch_bounds__(64) void kD(float* __restrict__ out,
                                         const float* __restrict__ ws)
{
    int lane = threadIdx.x;
    int unit = blockIdx.x;               // 0..719
    int bh = unit / NT_, u = unit - bh * NT_;
    int b = bh >> 3, h = bh & 7;

    const float4* mp4 = (const float4*)(ws + OFF_MPART + ((long)bh * NT_ + u) * NKC);
    const float4* sp4 = (const float4*)(ws + OFF_SPART + ((long)bh * NT_ + u) * NKC);

    float mc[NKC], sc[NKC];
    float m = NEG_BIG;
#pragma unroll
    for (int c4 = 0; c4 < NKC / 4; ++c4) {
        float4 mv = mp4[c4];
        float4 sv = sp4[c4];
        mc[c4 * 4 + 0] = mv.x; mc[c4 * 4 + 1] = mv.y;
        mc[c4 * 4 + 2] = mv.z; mc[c4 * 4 + 3] = mv.w;
        sc[c4 * 4 + 0] = sv.x; sc[c4 * 4 + 1] = sv.y;
        sc[c4 * 4 + 2] = sv.z; sc[c4 * 4 + 3] = sv.w;
        m = fmaxf(m, fmaxf(fmaxf(mv.x, mv.y), fmaxf(mv.z, mv.w)));
    }
    float T = 0.f, ctx = 0.f;
#pragma unroll
    for (int c = 0; c < NKC; ++c) {
        float wgt = __expf(mc[c] - m);   // fully-masked chunks: exp(-1e30-m) = 0
        T   += sc[c] * wgt;
        ctx += ws[OFF_CTXP + ((long)(bh * NKC + c) * NT_ + u) * 64 + lane] * wgt;
    }
    int qp = ((const int*)ws)[OFF_MTOP + bh * NT_ + u];
    out[((((long)b * L_ + qp) * H_ + h) << 6) + lane] = ctx / T;
}

// ---------------------------------------------------------------------------
extern "C" void kernel_launch(void* const* d_in, const int* in_sizes, int n_in,
                              void* d_out, int out_size, void* d_ws, size_t ws_size,
                              hipStream_t stream)
{
    const float* Q    = (const float*)d_in[0];
    const float* K    = (const float*)d_in[1];
    const float* V    = (const float*)d_in[2];
    const int*   samp = (const int*)d_in[4];   // d_in[3] = attn_mask (unused)
    float* out = (float*)d_out;
    float* ws  = (float*)d_ws;

    // A: M scores (16384 blocks = (b,q,hh), XCD-slab swizzled) + V chunk
    //    sums (512 blocks x 2 waves)
    kA<<<16896, 128, 0, stream>>>(Q, K, V, samp, ws);
    // B: top-45 (16 blocks) + cumsum write (256 blocks)
    kB<<<272, 256, 0, stream>>>(V, out, ws);
    // C: attention partials (16 bh x 32 key chunks x 2 u-halves)
    kC<<<1024, 256, 0, stream>>>(Q, K, V, ws);
    // D: merge + scatter selected rows (720 x 64-thread blocks)
    kD<<<720, 64, 0, stream>>>(out, ws);
}